// Round 10
// baseline (428.498 us; speedup 1.0000x reference)
//
#include <hip/hip_runtime.h>
#include <hip/hip_bf16.h>

// Problem constants
#define BATCH 4
#define SEQ   2048
#define DIM   1024      // D = H*HDIM
#define NHEAD 16
#define HDIM  64
#define EPS_LN 1e-5f
// 1/sqrt(64) * log2(e): folded into Q projection so attention can use exp2
#define QSCALE 0.18033688011112042f

typedef __attribute__((ext_vector_type(8))) short short8;   // 8 bf16 = 4 VGPR
typedef __attribute__((ext_vector_type(4))) float f32x4;    // MFMA acc

__device__ __forceinline__ unsigned short f2bf(float x) {
    __hip_bfloat16 h = __float2bfloat16(x);
    return *reinterpret_cast<unsigned short*>(&h);
}
__device__ __forceinline__ unsigned int pack2bf(float a, float b) {
    __hip_bfloat162 h = __float22bfloat162_rn(float2{a, b});
    return *reinterpret_cast<unsigned int*>(&h);
}

// async 16B global -> LDS (per-lane gptr; LDS dest must be wave-uniform-base + lane*16)
__device__ __forceinline__ void gl_lds16(const void* g, void* l) {
    __builtin_amdgcn_global_load_lds(
        (const __attribute__((address_space(1))) unsigned int*)g,
        (__attribute__((address_space(3))) unsigned int*)l,
        16, 0, 0);
}

// ---------------- prep: 4 weight transposes (z=0..3) + queries convert (z=4) ----------------
__global__ __launch_bounds__(256) void prep_kernel(const float* __restrict__ W0,
                                                   const float* __restrict__ W1,
                                                   const float* __restrict__ W2,
                                                   const float* __restrict__ W3,
                                                   const float* __restrict__ queries,
                                                   unsigned short* __restrict__ Wqkvt,
                                                   unsigned short* __restrict__ Wot,
                                                   unsigned short* __restrict__ qout)
{
    const int z = blockIdx.z;
    const int t = threadIdx.x;

    if (z == 4) {
        // bulk fp32 -> bf16 convert of queries: 8.39M floats = 2.097M float4
        const int nthr = 16 * 16 * 256;            // 65536
        int i = (blockIdx.y * 16 + blockIdx.x) * 256 + t;
        for (int it = 0; it < (BATCH * SEQ * DIM / 4) / nthr; it++, i += nthr) {
            float4 v = ((const float4*)queries)[i];
            ushort4 u;
            u.x = f2bf(v.x); u.y = f2bf(v.y); u.z = f2bf(v.z); u.w = f2bf(v.w);
            ((ushort4*)qout)[i] = u;
        }
        return;
    }

    __shared__ float Ts[64][65];
    const float* W = (z == 0) ? W0 : (z == 1) ? W1 : (z == 2) ? W2 : W3;
    unsigned short* Wt = (z == 3) ? Wot : (Wqkvt + (size_t)z * DIM * DIM);

    const int k0 = blockIdx.y * 64, n0 = blockIdx.x * 64;
    const int lr = t >> 2, lq = t & 3;

#pragma unroll
    for (int i = 0; i < 4; i++) {
        float4 v = *(const float4*)(W + (size_t)(k0 + lr) * DIM + n0 + (lq * 4 + i) * 4);
        Ts[lr][(lq * 4 + i) * 4 + 0] = v.x;
        Ts[lr][(lq * 4 + i) * 4 + 1] = v.y;
        Ts[lr][(lq * 4 + i) * 4 + 2] = v.z;
        Ts[lr][(lq * 4 + i) * 4 + 3] = v.w;
    }
    __syncthreads();
#pragma unroll
    for (int i = 0; i < 4; i++) {
        const int c = lq * 16 + i * 4;
        ushort4 u;
        u.x = f2bf(Ts[c + 0][lr]);
        u.y = f2bf(Ts[c + 1][lr]);
        u.z = f2bf(Ts[c + 2][lr]);
        u.w = f2bf(Ts[c + 3][lr]);
        *(ushort4*)(Wt + (size_t)(n0 + lr) * DIM + k0 + c) = u;
    }
}

// ---------------- fused QKV GEMM: [8192,1024] @ [3072,1024]^T ----------------
// sector 0: Qbf natural bf16, (acc+bq)*QSCALE
// sector 1: Kbf natural bf16, acc+bk
// sector 2: Vtb transposed-per-head: Vt[b][h][d][l], acc+bv
__global__ __launch_bounds__(256) void gemm_qkv(const unsigned short* __restrict__ A,
                                                const unsigned short* __restrict__ Bt,
                                                const float* __restrict__ bq,
                                                const float* __restrict__ bk,
                                                const float* __restrict__ bv,
                                                unsigned short* __restrict__ Qbf,
                                                unsigned short* __restrict__ Kbf,
                                                unsigned short* __restrict__ Vtb)
{
    __shared__ __attribute__((aligned(16))) unsigned short As[128 * 32];
    __shared__ __attribute__((aligned(16))) unsigned short Bs[128 * 32];

    const int tid = threadIdx.x;
    const int w = tid >> 6, lane = tid & 63;
    const int col = lane & 15, quad = lane >> 4;
    const int wm = (w >> 1) * 64, wn = (w & 1) * 64;
    const int m0 = blockIdx.y * 128, n0 = blockIdx.x * 128;

    f32x4 acc[4][4] = {};
    const int srow = tid >> 2, sc4 = tid & 3;

    for (int k0 = 0; k0 < DIM; k0 += 32) {
        __syncthreads();
#pragma unroll
        for (int it = 0; it < 2; it++) {
            gl_lds16(A  + (size_t)(m0 + srow + it * 64) * DIM + k0 + sc4 * 8,
                     (char*)As + w * 1024 + it * 4096);
            gl_lds16(Bt + (size_t)(n0 + srow + it * 64) * DIM + k0 + sc4 * 8,
                     (char*)Bs + w * 1024 + it * 4096);
        }
        __syncthreads();

        short8 af[4], bf[4];
#pragma unroll
        for (int mt = 0; mt < 4; mt++) af[mt] = *(short8*)&As[(wm + mt * 16 + col) * 32 + quad * 8];
#pragma unroll
        for (int nt = 0; nt < 4; nt++) bf[nt] = *(short8*)&Bs[(wn + nt * 16 + col) * 32 + quad * 8];

#pragma unroll
        for (int mt = 0; mt < 4; mt++)
#pragma unroll
            for (int nt = 0; nt < 4; nt++)
                acc[mt][nt] = __builtin_amdgcn_mfma_f32_16x16x32_bf16(af[mt], bf[nt], acc[mt][nt], 0, 0, 0);
    }

    const int sector = n0 >> 10;   // block never straddles (1024 % 128 == 0)
    const float* bias = (sector == 0) ? bq : (sector == 1) ? bk : bv;

#pragma unroll
    for (int nt = 0; nt < 4; nt++) {
        const int n = n0 + wn + nt * 16 + col;
        const int nloc = n - (sector << 10);
        const float bvv = bias[nloc];
#pragma unroll
        for (int mt = 0; mt < 4; mt++) {
            const int mbase = m0 + wm + mt * 16 + quad * 4;
            if (sector == 0) {
#pragma unroll
                for (int r = 0; r < 4; r++)
                    Qbf[(size_t)(mbase + r) * DIM + nloc] = f2bf((acc[mt][nt][r] + bvv) * QSCALE);
            } else if (sector == 1) {
#pragma unroll
                for (int r = 0; r < 4; r++)
                    Kbf[(size_t)(mbase + r) * DIM + nloc] = f2bf(acc[mt][nt][r] + bvv);
            } else {
                const int h = nloc >> 6, d = nloc & 63;
                const int b = mbase >> 11, l = mbase & 2047;
                ushort4 u;
                u.x = f2bf(acc[mt][nt][0] + bvv);
                u.y = f2bf(acc[mt][nt][1] + bvv);
                u.z = f2bf(acc[mt][nt][2] + bvv);
                u.w = f2bf(acc[mt][nt][3] + bvv);
                *(ushort4*)(Vtb + ((size_t)((b * NHEAD + h) * HDIM + d)) * SEQ + l) = u;
            }
        }
    }
}

// ---------------- out-proj GEMM: fp32 out = A @ Wot^T + bo + resid ----------------
__global__ __launch_bounds__(256) void gemm_out(const unsigned short* __restrict__ A,
                                                const unsigned short* __restrict__ Bt,
                                                const float* __restrict__ bias,
                                                const float* __restrict__ resid,
                                                float* __restrict__ Cout)
{
    __shared__ __attribute__((aligned(16))) unsigned short As[128 * 32];
    __shared__ __attribute__((aligned(16))) unsigned short Bs[128 * 32];

    const int tid = threadIdx.x;
    const int w = tid >> 6, lane = tid & 63;
    const int col = lane & 15, quad = lane >> 4;
    const int wm = (w >> 1) * 64, wn = (w & 1) * 64;
    const int m0 = blockIdx.y * 128, n0 = blockIdx.x * 128;

    f32x4 acc[4][4] = {};
    const int srow = tid >> 2, sc4 = tid & 3;

    for (int k0 = 0; k0 < DIM; k0 += 32) {
        __syncthreads();
#pragma unroll
        for (int it = 0; it < 2; it++) {
            gl_lds16(A  + (size_t)(m0 + srow + it * 64) * DIM + k0 + sc4 * 8,
                     (char*)As + w * 1024 + it * 4096);
            gl_lds16(Bt + (size_t)(n0 + srow + it * 64) * DIM + k0 + sc4 * 8,
                     (char*)Bs + w * 1024 + it * 4096);
        }
        __syncthreads();

        short8 af[4], bf[4];
#pragma unroll
        for (int mt = 0; mt < 4; mt++) af[mt] = *(short8*)&As[(wm + mt * 16 + col) * 32 + quad * 8];
#pragma unroll
        for (int nt = 0; nt < 4; nt++) bf[nt] = *(short8*)&Bs[(wn + nt * 16 + col) * 32 + quad * 8];

#pragma unroll
        for (int mt = 0; mt < 4; mt++)
#pragma unroll
            for (int nt = 0; nt < 4; nt++)
                acc[mt][nt] = __builtin_amdgcn_mfma_f32_16x16x32_bf16(af[mt], bf[nt], acc[mt][nt], 0, 0, 0);
    }

#pragma unroll
    for (int nt = 0; nt < 4; nt++) {
        const int n = n0 + wn + nt * 16 + col;
        const float bvv = bias[n];
#pragma unroll
        for (int mt = 0; mt < 4; mt++) {
            const int mbase = m0 + wm + mt * 16 + quad * 4;
#pragma unroll
            for (int r = 0; r < 4; r++) {
                const size_t off = (size_t)(mbase + r) * DIM + n;
                Cout[off] = acc[mt][nt][r] + bvv + resid[off];
            }
        }
    }
}

// ---------------- MFMA flash attention v7 ----------------
// Round-7 structure + (a) register-prefetch software pipeline for K/V staging,
// (b) XCD-swizzled block index (same-(b,h) blocks share an XCD's L2).
#define KP 72   // padded row stride in halfs (144 B)
__global__ __launch_bounds__(256) void attn_mfma(const unsigned short* __restrict__ Qb,
                                                 const unsigned short* __restrict__ Kb,
                                                 const unsigned short* __restrict__ Vt,
                                                 unsigned short* __restrict__ Ob)
{
    __shared__ __attribute__((aligned(16))) unsigned short Ks[64 * KP];      // [key][d]
    __shared__ __attribute__((aligned(16))) unsigned short Vs[64 * KP];      // [d][key]
    __shared__ __attribute__((aligned(16))) unsigned short Ps[4][32 * KP];   // per-wave [q_local][key]

    const int tid = threadIdx.x;
    const int w = tid >> 6, lane = tid & 63;
    const int col = lane & 15, quad = lane >> 4;

    // XCD swizzle: bh fastest -> the 16 q-blocks of one (b,h) all have the same
    // (blockIdx % 8), landing on one XCD whose 4MB L2 holds that head's K+V (512KB).
    const int bh  = blockIdx.x & 63;
    const int qt_ = blockIdx.x >> 6;
    const int b   = bh >> 4;
    const int h   = bh & 15;

    const int q0 = qt_ * 128 + w * 32;

    // Q B-fragments
    short8 qf[2][2];
#pragma unroll
    for (int qt = 0; qt < 2; qt++) {
        const size_t base = ((size_t)(b * SEQ) + q0 + qt * 16 + col) * DIM + h * HDIM + quad * 8;
        qf[qt][0] = *(const short8*)(Qb + base);
        qf[qt][1] = *(const short8*)(Qb + base + 32);
    }

    // ones A-fragment (row 0 = key-sum of P)
    short8 onesf;
    {
        const short v = (col == 0) ? (short)0x3F80 : (short)0;
        onesf = short8{v, v, v, v, v, v, v, v};
    }

    f32x4 o[4][2] = {};
    f32x4 od[2]   = {};

    const size_t kbase0 = ((size_t)(b * SEQ)) * DIM + h * HDIM;
    const size_t vbase0 = ((size_t)((b * NHEAD + h) * HDIM)) * SEQ;

    const int srow = tid >> 3, sc = tid & 7;
    unsigned short* Pw = Ps[w];

    // software pipeline: prefetch tile kt into registers; LDS-store at loop top.
    int4 kreg[2], vreg[2];
#pragma unroll
    for (int it = 0; it < 2; it++) {
        const int row = srow + it * 32;
        kreg[it] = *(const int4*)(Kb + kbase0 + (size_t)row * DIM + sc * 8);
        vreg[it] = *(const int4*)(Vt + vbase0 + (size_t)row * SEQ + sc * 8);
    }

    for (int kt = 0; kt < SEQ / 64; kt++) {
        __syncthreads();   // prior iteration's LDS reads complete
#pragma unroll
        for (int it = 0; it < 2; it++) {
            const int row = srow + it * 32;
            *(int4*)&Ks[row * KP + sc * 8] = kreg[it];
            *(int4*)&Vs[row * KP + sc * 8] = vreg[it];
        }
        __syncthreads();

        // prefetch next tile (latency hidden behind this tile's compute)
        if (kt + 1 < SEQ / 64) {
#pragma unroll
            for (int it = 0; it < 2; it++) {
                const int row = srow + it * 32;
                kreg[it] = *(const int4*)(Kb + kbase0 + (size_t)((kt + 1) * 64 + row) * DIM + sc * 8);
                vreg[it] = *(const int4*)(Vt + vbase0 + (size_t)row * SEQ + (kt + 1) * 64 + sc * 8);
            }
        }

        // S^T = K @ Q^T ; P = 2^S
#pragma unroll
        for (int nt = 0; nt < 4; nt++) {
            short8 kf0 = *(short8*)&Ks[(nt * 16 + col) * KP + quad * 8];
            short8 kf1 = *(short8*)&Ks[(nt * 16 + col) * KP + quad * 8 + 32];
#pragma unroll
            for (int qt = 0; qt < 2; qt++) {
                f32x4 s = {};
                s = __builtin_amdgcn_mfma_f32_16x16x32_bf16(kf0, qf[qt][0], s, 0, 0, 0);
                s = __builtin_amdgcn_mfma_f32_16x16x32_bf16(kf1, qf[qt][1], s, 0, 0, 0);
                const float p0 = __builtin_amdgcn_exp2f(s[0]);
                const float p1 = __builtin_amdgcn_exp2f(s[1]);
                const float p2 = __builtin_amdgcn_exp2f(s[2]);
                const float p3 = __builtin_amdgcn_exp2f(s[3]);
                uint2 pk;
                pk.x = pack2bf(p0, p1);
                pk.y = pack2bf(p2, p3);
                *(uint2*)&Pw[(qt * 16 + col) * KP + nt * 16 + quad * 4] = pk;
            }
        }

        // P^T B-fragments (wave-internal LDS round-trip)
        short8 pf[2][2];
#pragma unroll
        for (int qt = 0; qt < 2; qt++) {
            pf[qt][0] = *(short8*)&Pw[(qt * 16 + col) * KP + quad * 8];
            pf[qt][1] = *(short8*)&Pw[(qt * 16 + col) * KP + quad * 8 + 32];
        }

        // denominator rows (ones A-fragment MFMA)
#pragma unroll
        for (int qt = 0; qt < 2; qt++) {
            od[qt] = __builtin_amdgcn_mfma_f32_16x16x32_bf16(onesf, pf[qt][0], od[qt], 0, 0, 0);
            od[qt] = __builtin_amdgcn_mfma_f32_16x16x32_bf16(onesf, pf[qt][1], od[qt], 0, 0, 0);
        }

        // O^T += V^T @ P^T
#pragma unroll
        for (int mt = 0; mt < 4; mt++) {
            short8 vf0 = *(short8*)&Vs[(mt * 16 + col) * KP + quad * 8];
            short8 vf1 = *(short8*)&Vs[(mt * 16 + col) * KP + quad * 8 + 32];
#pragma unroll
            for (int qt = 0; qt < 2; qt++) {
                o[mt][qt] = __builtin_amdgcn_mfma_f32_16x16x32_bf16(vf0, pf[qt][0], o[mt][qt], 0, 0, 0);
                o[mt][qt] = __builtin_amdgcn_mfma_f32_16x16x32_bf16(vf1, pf[qt][1], o[mt][qt], 0, 0, 0);
            }
        }
    }

    // denom for q=col lives in od[qt][0] on quad-0 lane #col; broadcast
#pragma unroll
    for (int qt = 0; qt < 2; qt++) {
        const float den = __shfl(od[qt][0], col);
        const float inv = 1.f / den;
        const size_t rowoff = ((size_t)(b * SEQ) + q0 + qt * 16 + col) * DIM + h * HDIM;
#pragma unroll
        for (int mt = 0; mt < 4; mt++) {
            ushort4 u;
            u.x = f2bf(o[mt][qt][0] * inv);
            u.y = f2bf(o[mt][qt][1] * inv);
            u.z = f2bf(o[mt][qt][2] * inv);
            u.w = f2bf(o[mt][qt][3] * inv);
            *(ushort4*)(Ob + rowoff + mt * 16 + quad * 4) = u;
        }
    }
}

// ---------------- LayerNorm (in-place on d_out) ----------------
__global__ __launch_bounds__(256) void layernorm_kernel(float* __restrict__ res,
                                                        const float* __restrict__ gamma,
                                                        const float* __restrict__ beta)
{
    const int tid = threadIdx.x;
    const int row = blockIdx.x;
    float4 xv = ((const float4*)(res + (size_t)row * DIM))[tid];

    float s  = xv.x + xv.y + xv.z + xv.w;
    float sq = xv.x * xv.x + xv.y * xv.y + xv.z * xv.z + xv.w * xv.w;
#pragma unroll
    for (int off = 32; off; off >>= 1) {
        s  += __shfl_xor(s, off);
        sq += __shfl_xor(sq, off);
    }
    __shared__ float sm[8];
    const int w = tid >> 6, lane = tid & 63;
    if (lane == 0) { sm[w] = s; sm[4 + w] = sq; }
    __syncthreads();
    const float st  = sm[0] + sm[1] + sm[2] + sm[3];
    const float sqt = sm[4] + sm[5] + sm[6] + sm[7];
    const float mu   = st * (1.f / DIM);
    const float var  = sqt * (1.f / DIM) - mu * mu;
    const float rstd = rsqrtf(var + EPS_LN);

    float4 g  = ((const float4*)gamma)[tid];
    float4 be = ((const float4*)beta)[tid];
    float4 o;
    o.x = (xv.x - mu) * rstd * g.x + be.x;
    o.y = (xv.y - mu) * rstd * g.y + be.y;
    o.z = (xv.z - mu) * rstd * g.z + be.z;
    o.w = (xv.w - mu) * rstd * g.w + be.w;
    ((float4*)(res + (size_t)row * DIM))[tid] = o;
}

// ---------------- launch ----------------
extern "C" void kernel_launch(void* const* d_in, const int* in_sizes, int n_in,
                              void* d_out, int out_size, void* d_ws, size_t ws_size,
                              hipStream_t stream)
{
    const float* queries = (const float*)d_in[0];
    const float* Wq = (const float*)d_in[1];
    const float* bq = (const float*)d_in[2];
    const float* Wk = (const float*)d_in[3];
    const float* bk = (const float*)d_in[4];
    const float* Wv = (const float*)d_in[5];
    const float* bv = (const float*)d_in[6];
    const float* Wo = (const float*)d_in[7];
    const float* bo = (const float*)d_in[8];
    const float* gamma = (const float*)d_in[9];
    const float* beta  = (const float*)d_in[10];
    float* outp = (float*)d_out;

    const int M = BATCH * SEQ;                    // 8192
    const size_t BUF = (size_t)M * DIM;
    const size_t WSZ = (size_t)DIM * DIM;

    unsigned short* w0  = (unsigned short*)d_ws;
    unsigned short* qin = w0;                     // bf16 queries; later: attention output
    unsigned short* Qbf = w0 + BUF;
    unsigned short* Kbf = w0 + 2 * BUF;
    unsigned short* Vtb = w0 + 3 * BUF;
    unsigned short* Wqkvt = w0 + 4 * BUF;         // [3072][1024]
    unsigned short* Wot   = Wqkvt + 3 * WSZ;
    unsigned short* Obf = qin;                    // reuse

    dim3 blk(256);

    // z=0..3: weight transposes; z=4: queries fp32->bf16
    dim3 pgrid(DIM / 64, DIM / 64, 5);
    prep_kernel<<<pgrid, blk, 0, stream>>>(Wq, Wk, Wv, Wo, queries, Wqkvt, Wot, qin);

    dim3 qkvgrid(3 * DIM / 128, M / 128);         // (24, 64) = 1536 blocks
    gemm_qkv<<<qkvgrid, blk, 0, stream>>>(qin, Wqkvt, bq, bk, bv, Qbf, Kbf, Vtb);

    // 1024 blocks: swizzled decode (bh = idx & 63, qt = idx >> 6)
    attn_mfma<<<BATCH * NHEAD * (SEQ / 128), blk, 0, stream>>>(Qbf, Kbf, Vtb, Obf);

    dim3 ogrid(DIM / 128, M / 128);               // (8, 64)
    gemm_out<<<ogrid, blk, 0, stream>>>(Obf, Wot, bo, queries, outp);

    layernorm_kernel<<<M, blk, 0, stream>>>(outp, gamma, beta);
}

// Round 11
// 311.081 us; speedup vs baseline: 1.3775x; 1.3775x over previous
//
#include <hip/hip_runtime.h>
#include <hip/hip_bf16.h>

// Problem constants
#define BATCH 4
#define SEQ   2048
#define DIM   1024      // D = H*HDIM
#define NHEAD 16
#define HDIM  64
#define EPS_LN 1e-5f
// 1/sqrt(64) * log2(e): folded into Q projection so attention can use exp2
#define QSCALE 0.18033688011112042f

typedef __attribute__((ext_vector_type(8))) short short8;   // 8 bf16 = 4 VGPR
typedef __attribute__((ext_vector_type(4))) float f32x4;    // MFMA acc

__device__ __forceinline__ unsigned short f2bf(float x) {
    __hip_bfloat16 h = __float2bfloat16(x);
    return *reinterpret_cast<unsigned short*>(&h);
}
__device__ __forceinline__ unsigned int pack2bf(float a, float b) {
    __hip_bfloat162 h = __float22bfloat162_rn(float2{a, b});
    return *reinterpret_cast<unsigned int*>(&h);
}

// async 16B global -> LDS (per-lane gptr; LDS dest must be wave-uniform-base + lane*16)
__device__ __forceinline__ void gl_lds16(const void* g, void* l) {
    __builtin_amdgcn_global_load_lds(
        (const __attribute__((address_space(1))) unsigned int*)g,
        (__attribute__((address_space(3))) unsigned int*)l,
        16, 0, 0);
}

// ---------------- prep: 4 weight transposes (z=0..3) + queries convert (z=4) ----------------
__global__ __launch_bounds__(256) void prep_kernel(const float* __restrict__ W0,
                                                   const float* __restrict__ W1,
                                                   const float* __restrict__ W2,
                                                   const float* __restrict__ W3,
                                                   const float* __restrict__ queries,
                                                   unsigned short* __restrict__ Wqkvt,
                                                   unsigned short* __restrict__ Wot,
                                                   unsigned short* __restrict__ qout)
{
    const int z = blockIdx.z;
    const int t = threadIdx.x;

    if (z == 4) {
        // bulk fp32 -> bf16 convert of queries
        const int nthr = 16 * 16 * 256;            // 65536
        int i = (blockIdx.y * 16 + blockIdx.x) * 256 + t;
        for (int it = 0; it < (BATCH * SEQ * DIM / 4) / nthr; it++, i += nthr) {
            float4 v = ((const float4*)queries)[i];
            ushort4 u;
            u.x = f2bf(v.x); u.y = f2bf(v.y); u.z = f2bf(v.z); u.w = f2bf(v.w);
            ((ushort4*)qout)[i] = u;
        }
        return;
    }

    __shared__ float Ts[64][65];
    const float* W = (z == 0) ? W0 : (z == 1) ? W1 : (z == 2) ? W2 : W3;
    unsigned short* Wt = (z == 3) ? Wot : (Wqkvt + (size_t)z * DIM * DIM);

    const int k0 = blockIdx.y * 64, n0 = blockIdx.x * 64;
    const int lr = t >> 2, lq = t & 3;

#pragma unroll
    for (int i = 0; i < 4; i++) {
        float4 v = *(const float4*)(W + (size_t)(k0 + lr) * DIM + n0 + (lq * 4 + i) * 4);
        Ts[lr][(lq * 4 + i) * 4 + 0] = v.x;
        Ts[lr][(lq * 4 + i) * 4 + 1] = v.y;
        Ts[lr][(lq * 4 + i) * 4 + 2] = v.z;
        Ts[lr][(lq * 4 + i) * 4 + 3] = v.w;
    }
    __syncthreads();
#pragma unroll
    for (int i = 0; i < 4; i++) {
        const int c = lq * 16 + i * 4;
        ushort4 u;
        u.x = f2bf(Ts[c + 0][lr]);
        u.y = f2bf(Ts[c + 1][lr]);
        u.z = f2bf(Ts[c + 2][lr]);
        u.w = f2bf(Ts[c + 3][lr]);
        *(ushort4*)(Wt + (size_t)(n0 + lr) * DIM + k0 + c) = u;
    }
}

// ---------------- fused QKV GEMM: [8192,1024] @ [3072,1024]^T ----------------
// sector 0: Qbf natural bf16, (acc+bq)*QSCALE
// sector 1: Kbf natural bf16, acc+bk
// sector 2: Vtb transposed-per-head: Vt[b][h][d][l], acc+bv
__global__ __launch_bounds__(256) void gemm_qkv(const unsigned short* __restrict__ A,
                                                const unsigned short* __restrict__ Bt,
                                                const float* __restrict__ bq,
                                                const float* __restrict__ bk,
                                                const float* __restrict__ bv,
                                                unsigned short* __restrict__ Qbf,
                                                unsigned short* __restrict__ Kbf,
                                                unsigned short* __restrict__ Vtb)
{
    __shared__ __attribute__((aligned(16))) unsigned short As[128 * 32];
    __shared__ __attribute__((aligned(16))) unsigned short Bs[128 * 32];

    const int tid = threadIdx.x;
    const int w = tid >> 6, lane = tid & 63;
    const int col = lane & 15, quad = lane >> 4;
    const int wm = (w >> 1) * 64, wn = (w & 1) * 64;
    const int m0 = blockIdx.y * 128, n0 = blockIdx.x * 128;

    f32x4 acc[4][4] = {};
    const int srow = tid >> 2, sc4 = tid & 3;

    for (int k0 = 0; k0 < DIM; k0 += 32) {
        __syncthreads();
#pragma unroll
        for (int it = 0; it < 2; it++) {
            gl_lds16(A  + (size_t)(m0 + srow + it * 64) * DIM + k0 + sc4 * 8,
                     (char*)As + w * 1024 + it * 4096);
            gl_lds16(Bt + (size_t)(n0 + srow + it * 64) * DIM + k0 + sc4 * 8,
                     (char*)Bs + w * 1024 + it * 4096);
        }
        __syncthreads();

        short8 af[4], bf[4];
#pragma unroll
        for (int mt = 0; mt < 4; mt++) af[mt] = *(short8*)&As[(wm + mt * 16 + col) * 32 + quad * 8];
#pragma unroll
        for (int nt = 0; nt < 4; nt++) bf[nt] = *(short8*)&Bs[(wn + nt * 16 + col) * 32 + quad * 8];

#pragma unroll
        for (int mt = 0; mt < 4; mt++)
#pragma unroll
            for (int nt = 0; nt < 4; nt++)
                acc[mt][nt] = __builtin_amdgcn_mfma_f32_16x16x32_bf16(af[mt], bf[nt], acc[mt][nt], 0, 0, 0);
    }

    const int sector = n0 >> 10;   // block never straddles (1024 % 128 == 0)
    const float* bias = (sector == 0) ? bq : (sector == 1) ? bk : bv;

#pragma unroll
    for (int nt = 0; nt < 4; nt++) {
        const int n = n0 + wn + nt * 16 + col;
        const int nloc = n - (sector << 10);
        const float bvv = bias[nloc];
#pragma unroll
        for (int mt = 0; mt < 4; mt++) {
            const int mbase = m0 + wm + mt * 16 + quad * 4;
            if (sector == 0) {
#pragma unroll
                for (int r = 0; r < 4; r++)
                    Qbf[(size_t)(mbase + r) * DIM + nloc] = f2bf((acc[mt][nt][r] + bvv) * QSCALE);
            } else if (sector == 1) {
#pragma unroll
                for (int r = 0; r < 4; r++)
                    Kbf[(size_t)(mbase + r) * DIM + nloc] = f2bf(acc[mt][nt][r] + bvv);
            } else {
                const int h = nloc >> 6, d = nloc & 63;
                const int b = mbase >> 11, l = mbase & 2047;
                ushort4 u;
                u.x = f2bf(acc[mt][nt][0] + bvv);
                u.y = f2bf(acc[mt][nt][1] + bvv);
                u.z = f2bf(acc[mt][nt][2] + bvv);
                u.w = f2bf(acc[mt][nt][3] + bvv);
                *(ushort4*)(Vtb + ((size_t)((b * NHEAD + h) * HDIM + d)) * SEQ + l) = u;
            }
        }
    }
}

// ---------------- out-proj GEMM: fp32 out = A @ Wot^T + bo + resid ----------------
__global__ __launch_bounds__(256) void gemm_out(const unsigned short* __restrict__ A,
                                                const unsigned short* __restrict__ Bt,
                                                const float* __restrict__ bias,
                                                const float* __restrict__ resid,
                                                float* __restrict__ Cout)
{
    __shared__ __attribute__((aligned(16))) unsigned short As[128 * 32];
    __shared__ __attribute__((aligned(16))) unsigned short Bs[128 * 32];

    const int tid = threadIdx.x;
    const int w = tid >> 6, lane = tid & 63;
    const int col = lane & 15, quad = lane >> 4;
    const int wm = (w >> 1) * 64, wn = (w & 1) * 64;
    const int m0 = blockIdx.y * 128, n0 = blockIdx.x * 128;

    f32x4 acc[4][4] = {};
    const int srow = tid >> 2, sc4 = tid & 3;

    for (int k0 = 0; k0 < DIM; k0 += 32) {
        __syncthreads();
#pragma unroll
        for (int it = 0; it < 2; it++) {
            gl_lds16(A  + (size_t)(m0 + srow + it * 64) * DIM + k0 + sc4 * 8,
                     (char*)As + w * 1024 + it * 4096);
            gl_lds16(Bt + (size_t)(n0 + srow + it * 64) * DIM + k0 + sc4 * 8,
                     (char*)Bs + w * 1024 + it * 4096);
        }
        __syncthreads();

        short8 af[4], bf[4];
#pragma unroll
        for (int mt = 0; mt < 4; mt++) af[mt] = *(short8*)&As[(wm + mt * 16 + col) * 32 + quad * 8];
#pragma unroll
        for (int nt = 0; nt < 4; nt++) bf[nt] = *(short8*)&Bs[(wn + nt * 16 + col) * 32 + quad * 8];

#pragma unroll
        for (int mt = 0; mt < 4; mt++)
#pragma unroll
            for (int nt = 0; nt < 4; nt++)
                acc[mt][nt] = __builtin_amdgcn_mfma_f32_16x16x32_bf16(af[mt], bf[nt], acc[mt][nt], 0, 0, 0);
    }

#pragma unroll
    for (int nt = 0; nt < 4; nt++) {
        const int n = n0 + wn + nt * 16 + col;
        const float bvv = bias[n];
#pragma unroll
        for (int mt = 0; mt < 4; mt++) {
            const int mbase = m0 + wm + mt * 16 + quad * 4;
#pragma unroll
            for (int r = 0; r < 4; r++) {
                const size_t off = (size_t)(mbase + r) * DIM + n;
                Cout[off] = acc[mt][nt][r] + bvv + resid[off];
            }
        }
    }
}

// ---------------- MFMA flash attention v8 ----------------
// Round-9 proven body (plain staging, no reg prefetch) + XCD-swizzled blockIdx:
// the 16 q-blocks of one (b,h) share (blockIdx % 8) -> same XCD L2 holds that
// head's K+V (512 KB), FETCH 139 -> ~47 MB.
#define KP 72   // padded row stride in halfs (144 B)
__global__ __launch_bounds__(256) void attn_mfma(const unsigned short* __restrict__ Qb,
                                                 const unsigned short* __restrict__ Kb,
                                                 const unsigned short* __restrict__ Vt,
                                                 unsigned short* __restrict__ Ob)
{
    __shared__ __attribute__((aligned(16))) unsigned short Ks[64 * KP];      // [key][d]
    __shared__ __attribute__((aligned(16))) unsigned short Vs[64 * KP];      // [d][key]
    __shared__ __attribute__((aligned(16))) unsigned short Ps[4][32 * KP];   // per-wave [q_local][key]

    const int tid = threadIdx.x;
    const int w = tid >> 6, lane = tid & 63;
    const int col = lane & 15, quad = lane >> 4;

    const int bh  = blockIdx.x & 63;   // (b,h) fastest -> q-blocks of one head share an XCD
    const int qt_ = blockIdx.x >> 6;
    const int b   = bh >> 4;
    const int h   = bh & 15;

    const int q0 = qt_ * 128 + w * 32;

    // Q B-fragments
    short8 qf[2][2];
#pragma unroll
    for (int qt = 0; qt < 2; qt++) {
        const size_t base = ((size_t)(b * SEQ) + q0 + qt * 16 + col) * DIM + h * HDIM + quad * 8;
        qf[qt][0] = *(const short8*)(Qb + base);
        qf[qt][1] = *(const short8*)(Qb + base + 32);
    }

    // ones A-fragment (row 0 = key-sum of P)
    short8 onesf;
    {
        const short v = (col == 0) ? (short)0x3F80 : (short)0;
        onesf = short8{v, v, v, v, v, v, v, v};
    }

    f32x4 o[4][2] = {};
    f32x4 od[2]   = {};

    const size_t kbase0 = ((size_t)(b * SEQ)) * DIM + h * HDIM;
    const size_t vbase0 = ((size_t)((b * NHEAD + h) * HDIM)) * SEQ;

    const int srow = tid >> 3, sc = tid & 7;
    unsigned short* Pw = Ps[w];

    for (int kt = 0; kt < SEQ / 64; kt++) {
        __syncthreads();
#pragma unroll
        for (int it = 0; it < 2; it++) {
            const int row = srow + it * 32;
            *(int4*)&Ks[row * KP + sc * 8] = *(const int4*)(Kb + kbase0 + (size_t)(kt * 64 + row) * DIM + sc * 8);
            *(int4*)&Vs[row * KP + sc * 8] = *(const int4*)(Vt + vbase0 + (size_t)row * SEQ + kt * 64 + sc * 8);
        }
        __syncthreads();

        // S^T = K @ Q^T ; P = 2^S
#pragma unroll
        for (int nt = 0; nt < 4; nt++) {
            short8 kf0 = *(short8*)&Ks[(nt * 16 + col) * KP + quad * 8];
            short8 kf1 = *(short8*)&Ks[(nt * 16 + col) * KP + quad * 8 + 32];
#pragma unroll
            for (int qt = 0; qt < 2; qt++) {
                f32x4 s = {};
                s = __builtin_amdgcn_mfma_f32_16x16x32_bf16(kf0, qf[qt][0], s, 0, 0, 0);
                s = __builtin_amdgcn_mfma_f32_16x16x32_bf16(kf1, qf[qt][1], s, 0, 0, 0);
                const float p0 = __builtin_amdgcn_exp2f(s[0]);
                const float p1 = __builtin_amdgcn_exp2f(s[1]);
                const float p2 = __builtin_amdgcn_exp2f(s[2]);
                const float p3 = __builtin_amdgcn_exp2f(s[3]);
                uint2 pk;
                pk.x = pack2bf(p0, p1);
                pk.y = pack2bf(p2, p3);
                *(uint2*)&Pw[(qt * 16 + col) * KP + nt * 16 + quad * 4] = pk;
            }
        }

        // P^T B-fragments (wave-internal LDS round-trip)
        short8 pf[2][2];
#pragma unroll
        for (int qt = 0; qt < 2; qt++) {
            pf[qt][0] = *(short8*)&Pw[(qt * 16 + col) * KP + quad * 8];
            pf[qt][1] = *(short8*)&Pw[(qt * 16 + col) * KP + quad * 8 + 32];
        }

        // denominator rows (ones A-fragment MFMA)
#pragma unroll
        for (int qt = 0; qt < 2; qt++) {
            od[qt] = __builtin_amdgcn_mfma_f32_16x16x32_bf16(onesf, pf[qt][0], od[qt], 0, 0, 0);
            od[qt] = __builtin_amdgcn_mfma_f32_16x16x32_bf16(onesf, pf[qt][1], od[qt], 0, 0, 0);
        }

        // O^T += V^T @ P^T
#pragma unroll
        for (int mt = 0; mt < 4; mt++) {
            short8 vf0 = *(short8*)&Vs[(mt * 16 + col) * KP + quad * 8];
            short8 vf1 = *(short8*)&Vs[(mt * 16 + col) * KP + quad * 8 + 32];
#pragma unroll
            for (int qt = 0; qt < 2; qt++) {
                o[mt][qt] = __builtin_amdgcn_mfma_f32_16x16x32_bf16(vf0, pf[qt][0], o[mt][qt], 0, 0, 0);
                o[mt][qt] = __builtin_amdgcn_mfma_f32_16x16x32_bf16(vf1, pf[qt][1], o[mt][qt], 0, 0, 0);
            }
        }
    }

    // denom for q=col lives in od[qt][0] on quad-0 lane #col; broadcast
#pragma unroll
    for (int qt = 0; qt < 2; qt++) {
        const float den = __shfl(od[qt][0], col);
        const float inv = 1.f / den;
        const size_t rowoff = ((size_t)(b * SEQ) + q0 + qt * 16 + col) * DIM + h * HDIM;
#pragma unroll
        for (int mt = 0; mt < 4; mt++) {
            ushort4 u;
            u.x = f2bf(o[mt][qt][0] * inv);
            u.y = f2bf(o[mt][qt][1] * inv);
            u.z = f2bf(o[mt][qt][2] * inv);
            u.w = f2bf(o[mt][qt][3] * inv);
            *(ushort4*)(Ob + rowoff + mt * 16 + quad * 4) = u;
        }
    }
}

// ---------------- LayerNorm (in-place on d_out) ----------------
__global__ __launch_bounds__(256) void layernorm_kernel(float* __restrict__ res,
                                                        const float* __restrict__ gamma,
                                                        const float* __restrict__ beta)
{
    const int tid = threadIdx.x;
    const int row = blockIdx.x;
    float4 xv = ((const float4*)(res + (size_t)row * DIM))[tid];

    float s  = xv.x + xv.y + xv.z + xv.w;
    float sq = xv.x * xv.x + xv.y * xv.y + xv.z * xv.z + xv.w * xv.w;
#pragma unroll
    for (int off = 32; off; off >>= 1) {
        s  += __shfl_xor(s, off);
        sq += __shfl_xor(sq, off);
    }
    __shared__ float sm[8];
    const int w = tid >> 6, lane = tid & 63;
    if (lane == 0) { sm[w] = s; sm[4 + w] = sq; }
    __syncthreads();
    const float st  = sm[0] + sm[1] + sm[2] + sm[3];
    const float sqt = sm[4] + sm[5] + sm[6] + sm[7];
    const float mu   = st * (1.f / DIM);
    const float var  = sqt * (1.f / DIM) - mu * mu;
    const float rstd = rsqrtf(var + EPS_LN);

    float4 g  = ((const float4*)gamma)[tid];
    float4 be = ((const float4*)beta)[tid];
    float4 o;
    o.x = (xv.x - mu) * rstd * g.x + be.x;
    o.y = (xv.y - mu) * rstd * g.y + be.y;
    o.z = (xv.z - mu) * rstd * g.z + be.z;
    o.w = (xv.w - mu) * rstd * g.w + be.w;
    ((float4*)(res + (size_t)row * DIM))[tid] = o;
}

// ---------------- launch ----------------
extern "C" void kernel_launch(void* const* d_in, const int* in_sizes, int n_in,
                              void* d_out, int out_size, void* d_ws, size_t ws_size,
                              hipStream_t stream)
{
    const float* queries = (const float*)d_in[0];
    const float* Wq = (const float*)d_in[1];
    const float* bq = (const float*)d_in[2];
    const float* Wk = (const float*)d_in[3];
    const float* bk = (const float*)d_in[4];
    const float* Wv = (const float*)d_in[5];
    const float* bv = (const float*)d_in[6];
    const float* Wo = (const float*)d_in[7];
    const float* bo = (const float*)d_in[8];
    const float* gamma = (const float*)d_in[9];
    const float* beta  = (const float*)d_in[10];
    float* outp = (float*)d_out;

    const int M = BATCH * SEQ;                    // 8192
    const size_t BUF = (size_t)M * DIM;
    const size_t WSZ = (size_t)DIM * DIM;

    unsigned short* w0  = (unsigned short*)d_ws;
    unsigned short* qin = w0;                     // bf16 queries; later: attention output
    unsigned short* Qbf = w0 + BUF;
    unsigned short* Kbf = w0 + 2 * BUF;
    unsigned short* Vtb = w0 + 3 * BUF;
    unsigned short* Wqkvt = w0 + 4 * BUF;         // [3072][1024]
    unsigned short* Wot   = Wqkvt + 3 * WSZ;
    unsigned short* Obf = qin;                    // reuse

    dim3 blk(256);

    // z=0..3: weight transposes; z=4: queries fp32->bf16
    dim3 pgrid(DIM / 64, DIM / 64, 5);
    prep_kernel<<<pgrid, blk, 0, stream>>>(Wq, Wk, Wv, Wo, queries, Wqkvt, Wot, qin);

    dim3 qkvgrid(3 * DIM / 128, M / 128);         // (24, 64) = 1536 blocks
    gemm_qkv<<<qkvgrid, blk, 0, stream>>>(qin, Wqkvt, bq, bk, bv, Qbf, Kbf, Vtb);

    // 1024 blocks: swizzled decode (bh = idx & 63, qt = idx >> 6)
    attn_mfma<<<BATCH * NHEAD * (SEQ / 128), blk, 0, stream>>>(Qbf, Kbf, Vtb, Obf);

    dim3 ogrid(DIM / 128, M / 128);               // (8, 64)
    gemm_out<<<ogrid, blk, 0, stream>>>(Obf, Wot, bo, queries, outp);

    layernorm_kernel<<<M, blk, 0, stream>>>(outp, gamma, beta);
}